// Round 11
// baseline (358.057 us; speedup 1.0000x reference)
//
#include <hip/hip_runtime.h>

#define NCH 6
#define NX 32
#define PLANE 1024                  // 32x32 cells per x-plane
#define NCELL (NX * PLANE)
#define STEP_STRIDE (NCH * NCELL)   // floats per history slice
#define NTHREADS 256                // one y-stripe (8 rows x 32 z) of a plane
#define NBLOCKS 128                 // 32 planes x 4 y-stripes
#define RB 2                        // ring slots; (slot, sign-parity) = epoch mod 4

// DIRECTED-VALUE (scatter-form) protocol, R9-proven (absmax 0): producer
// computes phi_out[o] from OWN D+phi and ships 1 tagged u32 per crossing
// face; consumer assembles v[o]=clip(face value). Tag = sign bit
// (phi_out>=0); slot=epoch&1, parity=(epoch>>1)&1; mutual-partner skew<=1.
//
// SESSION LEDGER (stepper us): R10 gather 180.7 | R2 plane 247.7 F | R3 wave
// 190 N | R4 k=2 208 F | R5 scope+nt 182.3 NULL | R8 poll-slim 171.6 WIN |
// R9 scatter-form ~117 BIG WIN (dropped out of top-5; envelope-differenced).
// Model: per-step ~1.31us = store-drain + poll RT + OVERSHOOT(~RT/2) + tail.
//
// R10 package (attack overshoot + tail; arithmetic order UNCHANGED):
// (a) dual-batch pipelined poll: 2 batches in flight, check older while newer
//     flies -> re-check period ~RT/2, overshoot halves. No sleep (no long
//     waits exist in the lockstep graph; abort flag rides every batch).
// (b) raw s_barrier + lgkmcnt(0)-only fence instead of __syncthreads: the
//     compiler's barrier drains vmcnt(0), which would stall on the in-flight
//     spare batch and cancel (a). Only LDS needs ordering (ring is tagged).
//     sched_barrier(0) after, to pin post-barrier LDS reads (rule #18).
// (c) pre-poll channel prep: v4/v5 (shfl of own pz4/pz5) and the intra-wave
//     y-channel (partner row is in the SAME wave: shfl_xor 32 of kept pn2/pn3
//     registers) move before the poll; only one y-channel/thread still reads
//     LDS post-barrier. FMA chain stays R9's exact i-ascending order ->
//     bitwise-identical output (absmax 0.0).
// Predict: stepper ~102-108 (harness 330-340), FETCH 43->50-80MB (benign),
// WRITE ~135MB, absmax 0.0. If >=345 or absmax>0 -> revert R9, declare.
#define RING32_WORDS ((size_t)RB * 4 * NCELL)   // u32 words: slot x dir x cell
#define F_DONE 0

typedef unsigned long long u64;
typedef unsigned int u32;
typedef float fx4 __attribute__((ext_vector_type(4)));   // native vec for nt store

__device__ __forceinline__ u32 ld32(const u32* p) {
    return __hip_atomic_load(p, __ATOMIC_RELAXED, __HIP_MEMORY_SCOPE_AGENT);
}
__device__ __forceinline__ void st32(u32* p, u32 v) {
    __hip_atomic_store(p, v, __ATOMIC_RELAXED, __HIP_MEMORY_SCOPE_AGENT);
}
__device__ __forceinline__ int ldi(const int* p) {
    return __hip_atomic_load(p, __ATOMIC_RELAXED, __HIP_MEMORY_SCOPE_AGENT);
}
__device__ __forceinline__ void sti(int* p, int v) {
    __hip_atomic_store(p, v, __ATOMIC_RELAXED, __HIP_MEMORY_SCOPE_AGENT);
}
__device__ __forceinline__ u32 tagf(float a, unsigned P) {
    const u32 w = __float_as_uint(a);            // phi_out >= 0 -> sign free
    return P ? (w | 0x80000000u) : w;
}
__device__ __forceinline__ float untagf(u32 w) {
    return __uint_as_float(w & 0x7fffffffu);
}
__device__ __forceinline__ float clip01(float a) {
    return fminf(fmaxf(a, 0.0f), 1.0f);
}
// LDS-only barrier: orders tile/lds_dn without draining vmcnt (keeps the
// spare poll batch in flight across the barrier).
__device__ __forceinline__ void barrier_lds() {
    asm volatile("s_waitcnt lgkmcnt(0)" ::: "memory");
    __builtin_amdgcn_s_barrier();
    __builtin_amdgcn_sched_barrier(0);
}

__global__ void __launch_bounds__(NTHREADS)
BEMNA_V7_2_PhaseSpace_44117904064519_kernel(
    const float* __restrict__ D,
    const int* __restrict__ sx_p, const int* __restrict__ sy_p,
    const int* __restrict__ sz_p, const int* __restrict__ ex_p,
    const int* __restrict__ ey_p, const int* __restrict__ ez_p,
    const int* __restrict__ maxit_p,
    float* __restrict__ out,
    u32* __restrict__ ring,
    int* __restrict__ flags)
{
    __shared__ float tile[2][2][NTHREADS];     // ping-pong: [buf][0=n2,1=n3][tid]
    __shared__ int lds_dn;                     // post-poll uniform abort relay

    const int tid = (int)threadIdx.x;          // yl*32+z
    const int bx  = (int)blockIdx.x;
    const int x   = bx >> 2;                   // plane
    const int s   = bx & 3;                    // y-stripe
    const int yl  = tid >> 5;                  // 0..7
    const int z   = tid & 31;
    const int y   = (s << 3) + yl;
    const int cell = (x << 10) + (y << 5) + z;

    const int sx = *sx_p, sy = *sy_p, sz = *sz_p;
    const int ex = *ex_p, ey = *ey_p, ez = *ez_p;
    const int maxit = *maxit_p;
    const bool is_seed   = (cell == ((sx << 10) | (sy << 5) | sz));
    const bool is_target = (cell == ((ex << 10) | (ey << 5) | ez));

    // D at OWN cell (scatter form): always in-bounds, no masking needed.
    float dreg[NCH][NCH];
#pragma unroll
    for (int o = 0; o < NCH; ++o)
#pragma unroll
        for (int i = 0; i < NCH; ++i)
            dreg[o][i] = D[(size_t)(o * NCH + i) * NCELL + cell] + 0.95f;

    // ring roles: dir0 read by x+1 | dir1 by x-1 | dir2 by y+1 | dir3 by y-1.
    const bool has_xm  = (x >= 1), has_xp = (x <= 30);
    const bool edge_ym = (yl == 0), edge_yp = (yl == 7);
    const bool has_ym  = edge_ym && (y >= 1);   // poll dir2 @ cell-32
    const bool has_yp  = edge_yp && (y <= 30);  // poll dir3 @ cell+32
    const bool pub_d2  = edge_yp && (y <= 30);  // my dir2 read by stripe above
    const bool pub_d3  = edge_ym && (y >= 1);   // my dir3 read by stripe below
    const bool odd     = (yl & 1) != 0;         // wave = rows (2w, 2w+1)

    // ---- init: epoch 0 (slot 0, parity 0), hist slice 0 ----
    const float iv = is_seed ? 1.0f : 0.0f;
    float pn2, pn3, pz4, pz5;                  // own prev directed values (reg)
    {
        float po[NCH];
#pragma unroll
        for (int o = 0; o < NCH; ++o) {        // phi_0 = iv on ALL channels
            float a = 0.f;
#pragma unroll
            for (int i = 0; i < NCH; ++i) a = fmaf(dreg[o][i], iv, a);
            po[o] = a;
        }
        st32(ring + 0 * NCELL + cell, tagf(po[0], 0));
        st32(ring + 1 * NCELL + cell, tagf(po[1], 0));
        if (pub_d2) st32(ring + 2 * NCELL + cell, tagf(po[2], 0));
        if (pub_d3) st32(ring + 3 * NCELL + cell, tagf(po[3], 0));
        tile[0][0][tid] = po[2];
        tile[0][1][tid] = po[3];
        pn2 = po[2]; pn3 = po[3]; pz4 = po[4]; pz5 = po[5];
        float* outp = out + cell;
#pragma unroll
        for (int o = 0; o < NCH; ++o)
            __builtin_nontemporal_store(iv, outp + o * NCELL);
    }
    __syncthreads();                           // one-time full barrier is fine

    int tripped = 0;
    // iteration t consumes epoch-t directed values, produces phi_{t+1}
    for (int t = 0; t <= maxit - 2; ++t) {
        const u32* r = ring + (size_t)(t & 1) * 4 * NCELL;
        const unsigned P = (unsigned)((t >> 1) & 1);

        // ---- pre-poll: register-sourced channels (values identical to R9) --
        const float rz4 = __shfl_up(pz4, 1, 32);     // from z-1 (row = 32 lanes)
        const float rz5 = __shfl_down(pz5, 1, 32);   // from z+1
        const float v4 = (z >= 1)  ? clip01(rz4) : 0.0f;
        const float v5 = (z <= 30) ? clip01(rz5) : 0.0f;
        // intra-wave y-face: even row needs partner(odd) n3; odd needs n2
        const float sendw = odd ? pn3 : pn2;
        const float recvw = __shfl_xor(sendw, 32, 64);
        float v2 = 0.0f, v3 = 0.0f;
        if (odd) v2 = clip01(recvw); else v3 = clip01(recvw);

        // ---- dual-batch pipelined poll ----
        u32 wxm = 0, wxp = 0, wym = 0, wyp = 0; int dn = -1;
        {
            const u32* q0 = r + 0 * NCELL + cell - PLANE;
            const u32* q1 = r + 1 * NCELL + cell + PLANE;
            const u32* q2 = r + 2 * NCELL + cell - 32;
            const u32* q3 = r + 3 * NCELL + cell + 32;
            u32 axm = 0, axp = 0, aym = 0, ayp = 0;
            u32 bxm = 0, bxp = 0, bym = 0, byp = 0;
            int adn, bdn;
            if (has_xm) axm = ld32(q0);
            if (has_xp) axp = ld32(q1);
            if (has_ym) aym = ld32(q2);
            if (has_yp) ayp = ld32(q3);
            adn = ldi(&flags[F_DONE]);
            for (;;) {
                // issue B while A is checked
                if (has_xm) bxm = ld32(q0);
                if (has_xp) bxp = ld32(q1);
                if (has_ym) bym = ld32(q2);
                if (has_yp) byp = ld32(q3);
                bdn = ldi(&flags[F_DONE]);
                bool okr = true;
                if (has_xm) okr = okr & ((axm >> 31) == P);
                if (has_xp) okr = okr & ((axp >> 31) == P);
                if (has_ym) okr = okr & ((aym >> 31) == P);
                if (has_yp) okr = okr & ((ayp >> 31) == P);
                if ((adn >= 0 && t + 1 > adn) || __ballot(okr) == ~0ull) {
                    wxm = axm; wxp = axp; wym = aym; wyp = ayp; dn = adn; break;
                }
                // issue A while B is checked
                if (has_xm) axm = ld32(q0);
                if (has_xp) axp = ld32(q1);
                if (has_ym) aym = ld32(q2);
                if (has_yp) ayp = ld32(q3);
                adn = ldi(&flags[F_DONE]);
                okr = true;
                if (has_xm) okr = okr & ((bxm >> 31) == P);
                if (has_xp) okr = okr & ((bxp >> 31) == P);
                if (has_ym) okr = okr & ((bym >> 31) == P);
                if (has_yp) okr = okr & ((byp >> 31) == P);
                if ((bdn >= 0 && t + 1 > bdn) || __ballot(okr) == ~0ull) {
                    wxm = bxm; wxp = bxp; wym = bym; wyp = byp; dn = bdn; break;
                }
            }
        }
        if (tid == 0) lds_dn = dn;             // relay wave0's flag sample
        barrier_lds();                         // LDS-only fence: spare batch
                                               // stays in flight (no vmcnt drain)
        if (lds_dn >= 0 && t + 1 > lds_dn) break;   // block-uniform abort

        // ---- finish assembly (one y-channel from LDS or ring) ----
        const float v0 = has_xm ? clip01(untagf(wxm)) : 0.0f;
        const float v1 = has_xp ? clip01(untagf(wxp)) : 0.0f;
        if (odd) {   // v3: y+1 is next wave (LDS) or stripe edge (ring/0)
            v3 = (yl <= 5) ? clip01(tile[t & 1][1][tid + 32])
                           : (has_yp ? clip01(untagf(wyp)) : 0.0f);
        } else {     // v2: y-1 is prev wave (LDS) or stripe edge (ring/0)
            v2 = (yl >= 2) ? clip01(tile[t & 1][0][tid - 32])
                           : (has_ym ? clip01(untagf(wym)) : 0.0f);
        }

        // trip: phi_{t+1} is the frozen state -> done_step = t+1
        if (is_target && !tripped) {
            if (v0 + v1 + v2 + v3 + v4 + v5 > 0.01f) {
                sti(&flags[F_DONE], t + 1);
                tripped = 1;
            }
        }

        // ---- 36-FMA in R9's exact i-ascending order (bitwise identical) ----
        const float vv[NCH] = { v0, v1, v2, v3, v4, v5 };
        float n0 = 0.f, n1 = 0.f, n2 = 0.f, n3 = 0.f, n4 = 0.f, n5 = 0.f;
#pragma unroll
        for (int i = 0; i < NCH; ++i) {
            n0 = fmaf(dreg[0][i], vv[i], n0);
            n1 = fmaf(dreg[1][i], vv[i], n1);
            n2 = fmaf(dreg[2][i], vv[i], n2);
            n3 = fmaf(dreg[3][i], vv[i], n3);
            n4 = fmaf(dreg[4][i], vv[i], n4);
            n5 = fmaf(dreg[5][i], vv[i], n5);
        }

        // publish epoch t+1 FIRST (critical inter-block edge), then locals
        {
            const unsigned P1 = (unsigned)(((t + 1) >> 1) & 1);
            u32* w = ring + (size_t)((t + 1) & 1) * 4 * NCELL;
            st32(w + 0 * NCELL + cell, tagf(n0, P1));
            st32(w + 1 * NCELL + cell, tagf(n1, P1));
            if (pub_d2) st32(w + 2 * NCELL + cell, tagf(n2, P1));
            if (pub_d3) st32(w + 3 * NCELL + cell, tagf(n3, P1));
            tile[(t + 1) & 1][0][tid] = n2;
            tile[(t + 1) & 1][1][tid] = n3;
            pn2 = n2; pn3 = n3; pz4 = n4; pz5 = n5;
        }

        // history slice t+1 last, non-temporal: HBM acks overlap next poll
        {
            float* outp = out + (size_t)(t + 1) * STEP_STRIDE + cell;
            __builtin_nontemporal_store(v0, outp + 0 * NCELL);
            __builtin_nontemporal_store(v1, outp + 1 * NCELL);
            __builtin_nontemporal_store(v2, outp + 2 * NCELL);
            __builtin_nontemporal_store(v3, outp + 3 * NCELL);
            __builtin_nontemporal_store(v4, outp + 4 * NCELL);
            __builtin_nontemporal_store(v5, outp + 5 * NCELL);
        }
    }
}

// Read-once/write-many fill: one 16B lane per slice element. Each thread
// loads its element of the frozen slice out[tf] ONCE and streams it to
// slices tf+1..maxit-1, overwriting any stepper overshoot. nt stores via
// native ext_vector_type (HIP float4 is a class the builtin rejects).
__global__ void fill_kernel(const int* __restrict__ flags,
                            float* __restrict__ outf,
                            int total4)
{
    const int s4 = STEP_STRIDE / 4;
    const int maxit = total4 / s4;
    const int ds = flags[F_DONE];
    const int tf = (ds >= 1 && ds <= maxit - 1) ? ds : maxit - 1;
    const int idx = (int)blockIdx.x * (int)blockDim.x + (int)threadIdx.x;
    fx4* o4 = (fx4*)outf;
    const fx4 v = o4[(size_t)tf * s4 + idx];
    for (int t = tf + 1; t < maxit; ++t)
        __builtin_nontemporal_store(v, &o4[(size_t)t * s4 + idx]);
}

extern "C" void kernel_launch(void* const* d_in, const int* in_sizes, int n_in,
                              void* d_out, int out_size, void* d_ws, size_t ws_size,
                              hipStream_t stream)
{
    const float* D   = (const float*)d_in[0];
    const int* sx    = (const int*)d_in[1];
    const int* sy    = (const int*)d_in[2];
    const int* sz    = (const int*)d_in[3];
    const int* ex    = (const int*)d_in[4];
    const int* ey    = (const int*)d_in[5];
    const int* ez    = (const int*)d_in[6];
    const int* maxit = (const int*)d_in[7];
    float* out = (float*)d_out;

    u32* ring  = (u32*)d_ws;                   // 2 x 4 x 32768 x 4B = 1.0 MB
    int* flags = (int*)(ring + RING32_WORDS);

    // 128 blocks x 256 threads (x-plane x y-stripe); plain launch, tagged
    // dataflow sync. Co-residency by capacity (128 blocks << 256 CUs).
    BEMNA_V7_2_PhaseSpace_44117904064519_kernel<<<dim3(NBLOCKS), dim3(NTHREADS), 0, stream>>>(
        D, sx, sy, sz, ex, ey, ez, maxit, out, ring, flags);

    // one 16B lane per slice element: STEP_STRIDE/4 = 49152 threads
    const int total4 = out_size / 4;
    fill_kernel<<<dim3((STEP_STRIDE / 4) / 256), dim3(256), 0, stream>>>(
        flags, out, total4);
}

// Round 12
// 348.481 us; speedup vs baseline: 1.0275x; 1.0275x over previous
//
#include <hip/hip_runtime.h>

#define NCH 6
#define NX 32
#define PLANE 1024                  // 32x32 cells per x-plane
#define NCELL (NX * PLANE)
#define STEP_STRIDE (NCH * NCELL)   // floats per history slice
#define NTHREADS 256                // one y-stripe (8 rows x 32 z) of a plane
#define NBLOCKS 128                 // 32 planes x 4 y-stripes
#define RB 2                        // ring slots; (slot, sign-parity) = epoch mod 4

// R9 DIRECTED-VALUE (scatter-form) PROTOCOL — session-best (347.6us harness,
// absmax 0). Producer computes phi_out[o] from OWN D+phi and ships 1 tagged
// u32 per crossing face; consumer assembles v[o]=clip(face value). Tag =
// sign bit (phi_out>=0); slot=epoch&1, parity=(epoch>>1)&1; mutual-partner
// skew<=1; poison sign=1 tag-fails -> bootstrap-safe.
//
// FINAL SESSION LEDGER (stepper us, envelope-differenced where noted):
//   R10-prev gather 180.7 | R2 plane-blocks 247.7 F | R3 wave-blocks 190 N |
//   R4 k=2 batch 208 F | R5 agent-scope+nt 182.3 NULL | R8 poll-slim 171.6 W |
//   R9 scatter-form ~117 BIG WIN | R10 dual-batch poll ~128 F (REVERTED).
// R10 lesson: poll loads contend with publish stores at the coherence point;
// raising poll rate delays the store-visibility edge everyone waits on.
// Single-batch polling self-throttles to one batch per RT — keep it.
//
// EFFECTIVE ROOFLINE: ~1.31us/step x 89 inherent sequential CA steps.
// Per-step cost is the cross-XCD store->visibility->poll round trip,
// invariant across geometry/partners/batching/scope/L3/pipelining. The
// session's wins all came from shrinking ROUND CONTENTS (R8 flag-in-batch,
// R9 6x payload cut). Remaining dispatches > stepper are harness-owned
// poison memsets (147us @ 80% HBM peak).
#define RING32_WORDS ((size_t)RB * 4 * NCELL)   // u32 words: slot x dir x cell
#define F_DONE 0

typedef unsigned long long u64;
typedef unsigned int u32;
typedef float fx4 __attribute__((ext_vector_type(4)));   // native vec for nt store

__device__ __forceinline__ u32 ld32(const u32* p) {
    return __hip_atomic_load(p, __ATOMIC_RELAXED, __HIP_MEMORY_SCOPE_AGENT);
}
__device__ __forceinline__ void st32(u32* p, u32 v) {
    __hip_atomic_store(p, v, __ATOMIC_RELAXED, __HIP_MEMORY_SCOPE_AGENT);
}
__device__ __forceinline__ int ldi(const int* p) {
    return __hip_atomic_load(p, __ATOMIC_RELAXED, __HIP_MEMORY_SCOPE_AGENT);
}
__device__ __forceinline__ void sti(int* p, int v) {
    __hip_atomic_store(p, v, __ATOMIC_RELAXED, __HIP_MEMORY_SCOPE_AGENT);
}
__device__ __forceinline__ u32 tagf(float a, unsigned P) {
    const u32 w = __float_as_uint(a);            // phi_out >= 0 -> sign free
    return P ? (w | 0x80000000u) : w;
}
__device__ __forceinline__ float untagf(u32 w) {
    return __uint_as_float(w & 0x7fffffffu);
}

__global__ void __launch_bounds__(NTHREADS)
BEMNA_V7_2_PhaseSpace_44117904064519_kernel(
    const float* __restrict__ D,
    const int* __restrict__ sx_p, const int* __restrict__ sy_p,
    const int* __restrict__ sz_p, const int* __restrict__ ex_p,
    const int* __restrict__ ey_p, const int* __restrict__ ez_p,
    const int* __restrict__ maxit_p,
    float* __restrict__ out,
    u32* __restrict__ ring,
    int* __restrict__ flags)
{
    __shared__ float tile[2][2][NTHREADS];     // ping-pong: [buf][dir2/dir3][tid]
    __shared__ int lds_dn;                     // post-loop uniform abort relay

    const int tid = (int)threadIdx.x;          // yl*32+z
    const int bx  = (int)blockIdx.x;
    const int x   = bx >> 2;                   // plane
    const int s   = bx & 3;                    // y-stripe
    const int yl  = tid >> 5;                  // 0..7
    const int z   = tid & 31;
    const int y   = (s << 3) + yl;
    const int cell = (x << 10) + (y << 5) + z;

    const int sx = *sx_p, sy = *sy_p, sz = *sz_p;
    const int ex = *ex_p, ey = *ey_p, ez = *ez_p;
    const int maxit = *maxit_p;
    const bool is_seed   = (cell == ((sx << 10) | (sy << 5) | sz));
    const bool is_target = (cell == ((ex << 10) | (ey << 5) | ez));

    // D at OWN cell (scatter form): always in-bounds, no masking needed.
    float dreg[NCH][NCH];
#pragma unroll
    for (int o = 0; o < NCH; ++o)
#pragma unroll
        for (int i = 0; i < NCH; ++i)
            dreg[o][i] = D[(size_t)(o * NCH + i) * NCELL + cell] + 0.95f;

    // ring roles: dir0 read by x+1 | dir1 by x-1 | dir2 by y+1 (stripe above)
    // | dir3 by y-1 (stripe below). Boundary masking at ASSEMBLY (v=0).
    const bool has_xm  = (x >= 1), has_xp = (x <= 30);
    const bool edge_ym = (yl == 0), edge_yp = (yl == 7);
    const bool has_ym  = edge_ym && (y >= 1);   // poll dir2 @ cell-32
    const bool has_yp  = edge_yp && (y <= 30);  // poll dir3 @ cell+32
    const bool pub_d2  = edge_yp && (y <= 30);  // my dir2 read by stripe above
    const bool pub_d3  = edge_ym && (y >= 1);   // my dir3 read by stripe below

    // ---- init: epoch 0 (slot 0, parity 0), hist slice 0 ----
    const float iv = is_seed ? 1.0f : 0.0f;
    float pz4, pz5;                            // own z-dir values (in-register)
    {
        float po[NCH];
#pragma unroll
        for (int o = 0; o < NCH; ++o) {        // phi_0 = iv on ALL channels
            float a = 0.f;
#pragma unroll
            for (int i = 0; i < NCH; ++i) a = fmaf(dreg[o][i], iv, a);
            po[o] = a;
        }
        st32(ring + 0 * NCELL + cell, tagf(po[0], 0));
        st32(ring + 1 * NCELL + cell, tagf(po[1], 0));
        if (pub_d2) st32(ring + 2 * NCELL + cell, tagf(po[2], 0));
        if (pub_d3) st32(ring + 3 * NCELL + cell, tagf(po[3], 0));
        tile[0][0][tid] = po[2];
        tile[0][1][tid] = po[3];
        pz4 = po[4]; pz5 = po[5];
        float* outp = out + cell;
#pragma unroll
        for (int o = 0; o < NCH; ++o)
            __builtin_nontemporal_store(iv, outp + o * NCELL);
    }
    __syncthreads();                           // tile[0] visible

    int tripped = 0;
    // iteration t consumes epoch-t directed values, produces phi_{t+1}
    for (int t = 0; t <= maxit - 2; ++t) {
        const u32* r = ring + (size_t)(t & 1) * 4 * NCELL;
        const unsigned P = (unsigned)((t >> 1) & 1);

        u32 wxm = 0, wxp = 0, wym = 0, wyp = 0;
        int dn = -1, spins = 0;
        for (;;) {
            // batched poll: 2-3 u32 + flag -> one waitcnt, one L3 RT
            if (has_xm) wxm = ld32(r + 0 * NCELL + cell - PLANE);
            if (has_xp) wxp = ld32(r + 1 * NCELL + cell + PLANE);
            if (has_ym) wym = ld32(r + 2 * NCELL + cell - 32);
            if (has_yp) wyp = ld32(r + 3 * NCELL + cell + 32);
            dn = ldi(&flags[F_DONE]);          // same addr all lanes: broadcast
            bool okr = true;
            if (has_xm) okr = okr & ((wxm >> 31) == P);
            if (has_xp) okr = okr & ((wxp >> 31) == P);
            if (has_ym) okr = okr & ((wym >> 31) == P);
            if (has_yp) okr = okr & ((wyp >> 31) == P);
            if (dn >= 0 && t + 1 > dn) break;  // abort: data moot (wave-uniform)
            if (__ballot(okr) == ~0ull) break;
            if (spins++) __builtin_amdgcn_s_sleep(1);   // no sleep on 1st retry
        }
        if (tid == 0) lds_dn = dn;             // relay wave0's flag sample
        __syncthreads();                       // tile writes settled + lds_dn
        if (lds_dn >= 0 && t + 1 > lds_dn) break;   // block-uniform abort

        // ---- assemble phi_{t+1}: v[o] = clip(directed value from face o) ----
        float v[NCH];
        v[0] = has_xm ? untagf(wxm) : 0.0f;
        v[1] = has_xp ? untagf(wxp) : 0.0f;
        v[2] = edge_ym ? (has_ym ? untagf(wym) : 0.0f) : tile[t & 1][0][tid - 32];
        v[3] = edge_yp ? (has_yp ? untagf(wyp) : 0.0f) : tile[t & 1][1][tid + 32];
        const float s4 = __shfl_up(pz4, 1, 32);     // from z-1 (row = 32 lanes)
        const float s5 = __shfl_down(pz5, 1, 32);   // from z+1
        v[4] = (z >= 1)  ? s4 : 0.0f;
        v[5] = (z <= 30) ? s5 : 0.0f;
#pragma unroll
        for (int o = 0; o < NCH; ++o) v[o] = fminf(fmaxf(v[o], 0.0f), 1.0f);

        // trip: phi_{t+1} is the frozen state -> done_step = t+1
        if (is_target && !tripped) {
            if (v[0] + v[1] + v[2] + v[3] + v[4] + v[5] > 0.01f) {
                sti(&flags[F_DONE], t + 1);
                tripped = 1;
            }
        }

        // ---- produce directed values for epoch t+1 (own-cell D, 36 FMA) ----
        float n0 = 0.f, n1 = 0.f, n2 = 0.f, n3 = 0.f, n4 = 0.f, n5 = 0.f;
#pragma unroll
        for (int i = 0; i < NCH; ++i) {
            n0 = fmaf(dreg[0][i], v[i], n0);
            n1 = fmaf(dreg[1][i], v[i], n1);
            n2 = fmaf(dreg[2][i], v[i], n2);
            n3 = fmaf(dreg[3][i], v[i], n3);
            n4 = fmaf(dreg[4][i], v[i], n4);
            n5 = fmaf(dreg[5][i], v[i], n5);
        }

        // publish epoch t+1: fire-and-forget tagged u32 stores
        {
            const unsigned P1 = (unsigned)(((t + 1) >> 1) & 1);
            u32* w = ring + (size_t)((t + 1) & 1) * 4 * NCELL;
            st32(w + 0 * NCELL + cell, tagf(n0, P1));
            st32(w + 1 * NCELL + cell, tagf(n1, P1));
            if (pub_d2) st32(w + 2 * NCELL + cell, tagf(n2, P1));
            if (pub_d3) st32(w + 3 * NCELL + cell, tagf(n3, P1));
            tile[(t + 1) & 1][0][tid] = n2;
            tile[(t + 1) & 1][1][tid] = n3;
            pz4 = n4; pz5 = n5;
        }

        // history slice t+1 last, non-temporal: HBM acks overlap next poll
        {
            float* outp = out + (size_t)(t + 1) * STEP_STRIDE + cell;
#pragma unroll
            for (int o = 0; o < NCH; ++o)
                __builtin_nontemporal_store(v[o], outp + o * NCELL);
        }
    }
}

// Read-once/write-many fill: one 16B lane per slice element. Each thread
// loads its element of the frozen slice out[tf] ONCE and streams it to
// slices tf+1..maxit-1, overwriting any stepper overshoot. nt stores via
// native ext_vector_type (HIP float4 is a class the builtin rejects).
__global__ void fill_kernel(const int* __restrict__ flags,
                            float* __restrict__ outf,
                            int total4)
{
    const int s4 = STEP_STRIDE / 4;
    const int maxit = total4 / s4;
    const int ds = flags[F_DONE];
    const int tf = (ds >= 1 && ds <= maxit - 1) ? ds : maxit - 1;
    const int idx = (int)blockIdx.x * (int)blockDim.x + (int)threadIdx.x;
    fx4* o4 = (fx4*)outf;
    const fx4 v = o4[(size_t)tf * s4 + idx];
    for (int t = tf + 1; t < maxit; ++t)
        __builtin_nontemporal_store(v, &o4[(size_t)t * s4 + idx]);
}

extern "C" void kernel_launch(void* const* d_in, const int* in_sizes, int n_in,
                              void* d_out, int out_size, void* d_ws, size_t ws_size,
                              hipStream_t stream)
{
    const float* D   = (const float*)d_in[0];
    const int* sx    = (const int*)d_in[1];
    const int* sy    = (const int*)d_in[2];
    const int* sz    = (const int*)d_in[3];
    const int* ex    = (const int*)d_in[4];
    const int* ey    = (const int*)d_in[5];
    const int* ez    = (const int*)d_in[6];
    const int* maxit = (const int*)d_in[7];
    float* out = (float*)d_out;

    u32* ring  = (u32*)d_ws;                   // 2 x 4 x 32768 x 4B = 1.0 MB
    int* flags = (int*)(ring + RING32_WORDS);

    // 128 blocks x 256 threads (x-plane x y-stripe); plain launch, tagged
    // dataflow sync. Co-residency by capacity (128 blocks << 256 CUs).
    BEMNA_V7_2_PhaseSpace_44117904064519_kernel<<<dim3(NBLOCKS), dim3(NTHREADS), 0, stream>>>(
        D, sx, sy, sz, ex, ey, ez, maxit, out, ring, flags);

    // one 16B lane per slice element: STEP_STRIDE/4 = 49152 threads
    const int total4 = out_size / 4;
    fill_kernel<<<dim3((STEP_STRIDE / 4) / 256), dim3(256), 0, stream>>>(
        flags, out, total4);
}